// Round 10
// baseline (657.511 us; speedup 1.0000x reference)
//
#include <hip/hip_runtime.h>
#include <hip/hip_bf16.h>

#define T_LEN 200
#define F_IN 64
#define A_IN 128
#define H 100
#define H4 400
#define OUT_N 10
#define ROWS 8

typedef __attribute__((ext_vector_type(8))) short bf16x8;
typedef __attribute__((ext_vector_type(4))) float f32x4;

#define NLOG2E -1.4426950408889634f

__device__ __forceinline__ unsigned short f2bf(float f) {
    union { float f; unsigned u; } v; v.f = f;
    unsigned r = v.u + 0x7FFFu + ((v.u >> 16) & 1u);
    return (unsigned short)(r >> 16);
}

__device__ __forceinline__ unsigned cvtpk(float lo, float hi) {
    unsigned r;
    asm("v_cvt_pk_bf16_f32 %0, %1, %2" : "=v"(r) : "v"(lo), "v"(hi));
    return r;
}

// sigmoid(z) where zp = -log2(e)*z came out of the MFMA (weights pre-scaled)
__device__ __forceinline__ float sigm2(float zp) {
    return __builtin_amdgcn_rcpf(1.0f + __builtin_amdgcn_exp2f(zp));
}

// LDS-only barrier: do NOT drain vmcnt (seq prefetch stays in flight)
__device__ __forceinline__ void lds_barrier() {
    asm volatile("s_waitcnt lgkmcnt(0)" ::: "memory");
    __builtin_amdgcn_s_barrier();
}

// h fragment slot for (batch b, hidden j): B-frag col=lane&15=b, k=lg*8+i
#define HOFF(b, j) ((((j) >> 5) * 64 + ((b) + 16 * (((j) >> 3) & 3))) * 8 + ((j) & 7))

extern "C" __global__ void __launch_bounds__(512, 4)
traj_kernel(const float* __restrict__ attrs, const float* __restrict__ seq,
            const float* __restrict__ Wd, const float* __restrict__ bd,
            const float* __restrict__ Wk, const float* __restrict__ Wr,
            const float* __restrict__ bl, const float* __restrict__ W1,
            const float* __restrict__ b1, const float* __restrict__ W2,
            const float* __restrict__ b2, const float* __restrict__ Wc,
            const float* __restrict__ bc, float* __restrict__ out)
{
    // LDS map (bytes), total 66688 (x2 blocks/CU = 133376 <= 160 KB):
    //   [0, 51200)       wkl   Wk A-frags: tile*2048 + kt*1024 + lane*16 (wave-private)
    //   [51200, 55296)   wr24  Wr A-frags tile 24: kt*1024 + lane*16 (wave-7-private)
    //   [55296, 63488)   hl    ushort[2][2048]  h bf16 B-frag double buffer
    //   [63488, 66688)   h32   float[8][100]    final h fp32
    // epilogue aliases (wkl dead): att [8][136]@0, catb [8][204]@4352,
    //   x1b [8][100]@10880, x2b [8][50]@14080, lgb [8][10]@15680
    __shared__ __align__(16) char smem[66688];
    unsigned short* hl = (unsigned short*)(smem + 55296);
    float* h32 = (float*)(smem + 63488);

    const int tid = threadIdx.x;
    const int lane = tid & 63;
    const int w = tid >> 6;            // 8 waves
    const int ln15 = lane & 15;
    const int lg = lane >> 4;
    const int b0 = blockIdx.x * ROWS;

    // reg-tiles: wave w owns {3w, 3w+1, 3w+2}; wave 7 also owns tile 24 via LDS
    const int nt0 = 3 * w;
    const bool w7 = (w == 7);

    // A-frag: lane holds row m=lane&15, k=(lane>>4)*8+i. Permuted row p=tile*16+m
    // -> original column c=(tile*4+(m>>2))+100*(m&3); D rows lg*4+r = gates i,f,g,o
    // of hidden j=tile*4+lg. Gates i,f,o pre-scaled by -log2(e) for exp2 sigmoid.
    const int rw = ln15 & 3;
    const int qr = ln15 >> 2;
    const float gsc = (rw == 2) ? 1.0f : NLOG2E;

    // ---- Wk frags -> LDS (own tiles; w7 also tile 24) ----
    {
        const int ntw = w7 ? 4 : 3;
        for (int q = 0; q < ntw; q++) {
            const int tile = (q == 3) ? 24 : nt0 + q;
            const int c = (tile * 4 + qr) + 100 * rw;
#pragma unroll
            for (int kt = 0; kt < 2; kt++) {
                bf16x8 f;
#pragma unroll
                for (int i = 0; i < 8; i++) {
                    int k = kt * 32 + lg * 8 + i;
                    f[i] = (short)f2bf(gsc * Wk[k * H4 + c]);
                }
                *(bf16x8*)(smem + tile * 2048 + kt * 1024 + lane * 16) = f;
            }
        }
        if (w7) {   // tile-24 Wr frags -> LDS (wave-private), bias in k==100
            const int c = (24 * 4 + qr) + 100 * rw;
#pragma unroll
            for (int kt = 0; kt < 4; kt++) {
                bf16x8 f;
#pragma unroll
                for (int i = 0; i < 8; i++) {
                    int k = kt * 32 + lg * 8 + i;
                    float x = 0.0f;
                    if (k < H) x = gsc * Wr[k * H4 + c];
                    if (k == H) x = gsc * bl[c];
                    f[i] = (short)f2bf(x);
                }
                *(bf16x8*)(smem + 51200 + kt * 1024 + lane * 16) = f;
            }
        }
    }

    // ---- Wr frags in registers (3 tiles), bias folded into spare K-row k==100 ----
    bf16x8 wrf[3][4];
#pragma unroll
    for (int q = 0; q < 3; q++) {
        const int c = ((nt0 + q) * 4 + qr) + 100 * rw;
#pragma unroll
        for (int kt = 0; kt < 4; kt++) {
            bf16x8 f;
#pragma unroll
            for (int i = 0; i < 8; i++) {
                int k = kt * 32 + lg * 8 + i;
                float x = 0.0f;
                if (k < H) x = gsc * Wr[k * H4 + c];
                if (k == H) x = gsc * bl[c];   // bias row (h slot k=100 pinned to 1)
                f[i] = (short)f2bf(x);
            }
            wrf[q][kt] = f;
        }
    }

    // gate destinations: batch b = ln15 (8..15 confined garbage), hidden j
    const int ho0 = HOFF(ln15, nt0 * 4 + lg);
    const int ho1 = HOFF(ln15, (nt0 + 1) * 4 + lg);
    const int ho2 = HOFF(ln15, (nt0 + 2) * 4 + lg);
    const int ho3 = HOFF(ln15, 96 + lg);     // w7's tile 24
    float cr0 = 0.f, cr1 = 0.f, cr2 = 0.f, cr3 = 0.f;
    float hq0 = 0.f, hq1 = 0.f, hq2 = 0.f, hq3 = 0.f;

    // zero both h buffers, then pin bias slot k=100 to bf16(1.0) in both
    for (int i = tid; i < 4096; i += 512) hl[i] = 0;
    __syncthreads();
    if (tid < 32) {
        int b = tid & 15, buf = tid >> 4;
        hl[buf * 2048 + 1536 + 8 * b + 4] = 0x3F80;  // (k=100, batch b) = 1.0
    }

    // ---- seq staging: lane = batch row ln15 (clamped), feats lg*8..+7, 32+lg*8..+7
    int brow = b0 + ln15; if (brow > 4095) brow = 4095;
    const float* sp = seq + (size_t)brow * (T_LEN * F_IN) + lg * 8;
    f32x4 s0 = *(const f32x4*)(sp);
    f32x4 s1 = *(const f32x4*)(sp + 4);
    f32x4 s2 = *(const f32x4*)(sp + 32);
    f32x4 s3 = *(const f32x4*)(sp + 36);
    sp += F_IN;

    const char* wkp = smem + nt0 * 2048 + lane * 16;  // own Wk base (+q*2048/+1024 imm)
    const char* w4p = smem + 51200 + lane * 16;       // tile-24 Wr base (w7)
    f32x4 accX0, accX1, accX2, accX3;

    // prologue: accX = x(0)@Wk^T (C=0; bias arrives via Wr k=100 each step)
    {
        union { unsigned u[4]; bf16x8 v; } ua, ub;
        ua.u[0] = cvtpk(s0[0], s0[1]); ua.u[1] = cvtpk(s0[2], s0[3]);
        ua.u[2] = cvtpk(s1[0], s1[1]); ua.u[3] = cvtpk(s1[2], s1[3]);
        ub.u[0] = cvtpk(s2[0], s2[1]); ub.u[1] = cvtpk(s2[2], s2[3]);
        ub.u[2] = cvtpk(s3[0], s3[1]); ub.u[3] = cvtpk(s3[2], s3[3]);
        bf16x8 a0 = ua.v, a1 = ub.v;
        const f32x4 zz = { 0.f, 0.f, 0.f, 0.f };
#define WKMM(OFF, DST, A0, A1) do {                                          \
            bf16x8 _wa = *(const bf16x8*)(wkp + (OFF));                      \
            bf16x8 _wb = *(const bf16x8*)(wkp + (OFF) + 1024);               \
            f32x4 _x = __builtin_amdgcn_mfma_f32_16x16x32_bf16(_wa, A0, zz, 0, 0, 0); \
            DST = __builtin_amdgcn_mfma_f32_16x16x32_bf16(_wb, A1, _x, 0, 0, 0);      \
        } while (0)
        WKMM(0,    accX0, a0, a1);
        WKMM(2048, accX1, a0, a1);
        WKMM(4096, accX2, a0, a1);
        if (w7) {
            bf16x8 _wa = *(const bf16x8*)(smem + 24 * 2048 + lane * 16);
            bf16x8 _wb = *(const bf16x8*)(smem + 24 * 2048 + 1024 + lane * 16);
            f32x4 _x = __builtin_amdgcn_mfma_f32_16x16x32_bf16(_wa, a0, zz, 0, 0, 0);
            accX3 = __builtin_amdgcn_mfma_f32_16x16x32_bf16(_wb, a1, _x, 0, 0, 0);
        }
    }
    // issue load of x(1)
    s0 = *(const f32x4*)(sp);
    s1 = *(const f32x4*)(sp + 4);
    s2 = *(const f32x4*)(sp + 32);
    s3 = *(const f32x4*)(sp + 36);
    sp += F_IN;

    lds_barrier();   // hl zeros + bias pins visible (seq loads stay in flight)

    for (int t = 0; t < T_LEN; t++) {
        const bool notlast = (t < T_LEN - 1);

        // ---- read h(t-1) B-frags from buf[t&1]; w7 also tile-24 Wr frags ----
        const unsigned short* hp = hl + ((t & 1) << 11) + lane * 8;
        bf16x8 hf0 = *(const bf16x8*)(hp);
        bf16x8 hf1 = *(const bf16x8*)(hp + 512);
        bf16x8 hf2 = *(const bf16x8*)(hp + 1024);
        bf16x8 hf3 = *(const bf16x8*)(hp + 1536);
        bf16x8 w40, w41, w42, w43;
        if (w7) {
            w40 = *(const bf16x8*)(w4p);
            w41 = *(const bf16x8*)(w4p + 1024);
            w42 = *(const bf16x8*)(w4p + 2048);
            w43 = *(const bf16x8*)(w4p + 3072);
        }

        // cvt x(t+1) (overlaps LDS read latency)
        bf16x8 a0n = {}, a1n = {};
        if (notlast) {
            union { unsigned u[4]; bf16x8 v; } ua, ub;
            ua.u[0] = cvtpk(s0[0], s0[1]); ua.u[1] = cvtpk(s0[2], s0[3]);
            ua.u[2] = cvtpk(s1[0], s1[1]); ua.u[3] = cvtpk(s1[2], s1[3]);
            ub.u[0] = cvtpk(s2[0], s2[1]); ub.u[1] = cvtpk(s2[2], s2[3]);
            ub.u[2] = cvtpk(s3[0], s3[1]); ub.u[3] = cvtpk(s3[2], s3[3]);
            a0n = ua.v; a1n = ub.v;
        }

        // ---- accX += h(t-1)@Wr^T in place (+bias via k=100); kt-major ILP ----
        __builtin_amdgcn_s_setprio(1);
        accX0 = __builtin_amdgcn_mfma_f32_16x16x32_bf16(wrf[0][0], hf0, accX0, 0, 0, 0);
        accX1 = __builtin_amdgcn_mfma_f32_16x16x32_bf16(wrf[1][0], hf0, accX1, 0, 0, 0);
        accX2 = __builtin_amdgcn_mfma_f32_16x16x32_bf16(wrf[2][0], hf0, accX2, 0, 0, 0);
        if (w7) accX3 = __builtin_amdgcn_mfma_f32_16x16x32_bf16(w40, hf0, accX3, 0, 0, 0);
        accX0 = __builtin_amdgcn_mfma_f32_16x16x32_bf16(wrf[0][1], hf1, accX0, 0, 0, 0);
        accX1 = __builtin_amdgcn_mfma_f32_16x16x32_bf16(wrf[1][1], hf1, accX1, 0, 0, 0);
        accX2 = __builtin_amdgcn_mfma_f32_16x16x32_bf16(wrf[2][1], hf1, accX2, 0, 0, 0);
        if (w7) accX3 = __builtin_amdgcn_mfma_f32_16x16x32_bf16(w41, hf1, accX3, 0, 0, 0);
        accX0 = __builtin_amdgcn_mfma_f32_16x16x32_bf16(wrf[0][2], hf2, accX0, 0, 0, 0);
        accX1 = __builtin_amdgcn_mfma_f32_16x16x32_bf16(wrf[1][2], hf2, accX1, 0, 0, 0);
        accX2 = __builtin_amdgcn_mfma_f32_16x16x32_bf16(wrf[2][2], hf2, accX2, 0, 0, 0);
        if (w7) accX3 = __builtin_amdgcn_mfma_f32_16x16x32_bf16(w42, hf2, accX3, 0, 0, 0);
        accX0 = __builtin_amdgcn_mfma_f32_16x16x32_bf16(wrf[0][3], hf3, accX0, 0, 0, 0);
        accX1 = __builtin_amdgcn_mfma_f32_16x16x32_bf16(wrf[1][3], hf3, accX1, 0, 0, 0);
        accX2 = __builtin_amdgcn_mfma_f32_16x16x32_bf16(wrf[2][3], hf3, accX2, 0, 0, 0);
        if (w7) accX3 = __builtin_amdgcn_mfma_f32_16x16x32_bf16(w43, hf3, accX3, 0, 0, 0);
        __builtin_amdgcn_s_setprio(0);

        // prefetch x(t+2) (rides across the LDS barrier)
        if (t < T_LEN - 2) {
            s0 = *(const f32x4*)(sp);
            s1 = *(const f32x4*)(sp + 4);
            s2 = *(const f32x4*)(sp + 32);
            s3 = *(const f32x4*)(sp + 36);
            sp += F_IN;
        }

        // ---- gates in registers; write h(t) bf16 to buf[(t+1)&1] ----
        unsigned short* hwp = hl + (((t + 1) & 1) << 11);

#define DOGATE(AX, CR, HQ, HO) do {                                    \
            float _i = sigm2(AX[0]), _f = sigm2(AX[1]);                \
            float _g = fmaxf(AX[2], 0.0f), _o = sigm2(AX[3]);          \
            CR = _f * CR + _i * _g;                                    \
            float _h = _o * fmaxf(CR, 0.0f);                           \
            HQ = _h;                                                   \
            hwp[HO] = (unsigned short)cvtpk(_h, _h);                   \
        } while (0)

        DOGATE(accX0, cr0, hq0, ho0);
        DOGATE(accX1, cr1, hq1, ho1);
        DOGATE(accX2, cr2, hq2, ho2);
        if (w7) DOGATE(accX3, cr3, hq3, ho3);

        // ---- accX = x(t+1)@Wk^T from LDS (overlaps gate VALU) ----
        if (notlast) {
            const f32x4 zz = { 0.f, 0.f, 0.f, 0.f };
            WKMM(0,    accX0, a0n, a1n);
            WKMM(2048, accX1, a0n, a1n);
            WKMM(4096, accX2, a0n, a1n);
            if (w7) {
                bf16x8 _wa = *(const bf16x8*)(smem + 24 * 2048 + lane * 16);
                bf16x8 _wb = *(const bf16x8*)(smem + 24 * 2048 + 1024 + lane * 16);
                f32x4 _x = __builtin_amdgcn_mfma_f32_16x16x32_bf16(_wa, a0n, zz, 0, 0, 0);
                accX3 = __builtin_amdgcn_mfma_f32_16x16x32_bf16(_wb, a1n, _x, 0, 0, 0);
            }
        }

        lds_barrier();   // h(t) visible; protects buf WAR; vmem stays in flight
    }

    // ---- final h -> h32 (from persistent registers; real rows only) ----
    if (ln15 < 8) {
        h32[ln15 * H + nt0 * 4 + lg]       = hq0;
        h32[ln15 * H + (nt0 + 1) * 4 + lg] = hq1;
        h32[ln15 * H + (nt0 + 2) * 4 + lg] = hq2;
        if (w7) h32[ln15 * H + 96 + lg]    = hq3;
    }

    // ---- epilogue: fp32 dense chain + softmax (ROWS=8, 512 threads) ----
    float* att  = (float*)smem;            // [8][136]
    float* catb = (float*)(smem + 4352);   // [8][204]
    float* x1b  = (float*)(smem + 10880);  // [8][100]
    float* x2b  = (float*)(smem + 14080);  // [8][50]
    float* lgb  = (float*)(smem + 15680);  // [8][10]

    if (tid < 256) {
        f32x4 v = ((const f32x4*)(attrs + (size_t)b0 * A_IN))[tid];  // 8x128 floats
        int row = tid >> 5, c4 = tid & 31;
        *(f32x4*)(att + row * 136 + c4 * 4) = v;
    }
    __syncthreads();

#pragma unroll
    for (int k = 0; k < 2; k++) {
        int e = tid + 512 * k;
        if (e < ROWS * H) {
            int b = e & 7, j = e >> 3;
            float s = bd[j];
            for (int kk = 0; kk < A_IN; kk++) s += att[b * 136 + kk] * Wd[kk * H + j];
            catb[b * 204 + j] = fmaxf(s, 0.0f);
            catb[b * 204 + H + j] = h32[b * H + j];
        }
    }
    __syncthreads();

#pragma unroll
    for (int k = 0; k < 2; k++) {
        int e = tid + 512 * k;
        if (e < ROWS * H) {
            int b = e & 7, j = e >> 3;
            float s = b1[j];
            for (int kk = 0; kk < 200; kk++) s += catb[b * 204 + kk] * W1[kk * H + j];
            x1b[b * H + j] = fmaxf(s, 0.0f);
        }
    }
    __syncthreads();

    if (tid < ROWS * 50) {
        int b = tid & 7, j = tid >> 3;
        float s = b2[j];
        for (int kk = 0; kk < H; kk++) s += x1b[b * H + kk] * W2[kk * 50 + j];
        x2b[b * 50 + j] = fmaxf(s, 0.0f);
    }
    __syncthreads();

    if (tid < ROWS * OUT_N) {
        int b = tid / OUT_N, o = tid % OUT_N;
        float s = bc[o];
        for (int kk = 0; kk < 50; kk++) s += x2b[b * 50 + kk] * Wc[kk * OUT_N + o];
        lgb[b * OUT_N + o] = s;
    }
    __syncthreads();

    if (tid < ROWS) {
        int b = tid;
        float m = -1e30f, v[10];
#pragma unroll
        for (int o = 0; o < 10; o++) { v[o] = lgb[b * 10 + o]; m = fmaxf(m, v[o]); }
        float ssum = 0.0f;
#pragma unroll
        for (int o = 0; o < 10; o++) { v[o] = __expf(v[o] - m); ssum += v[o]; }
        float inv = 1.0f / ssum;
#pragma unroll
        for (int o = 0; o < 10; o++) out[(size_t)(b0 + b) * 10 + o] = v[o] * inv;
    }
}

extern "C" void kernel_launch(void* const* d_in, const int* in_sizes, int n_in,
                              void* d_out, int out_size, void* d_ws, size_t ws_size,
                              hipStream_t stream) {
    const float* attrs = (const float*)d_in[0];
    const float* seq   = (const float*)d_in[1];
    const float* Wd    = (const float*)d_in[2];
    const float* bd    = (const float*)d_in[3];
    const float* Wk    = (const float*)d_in[4];
    const float* Wr    = (const float*)d_in[5];
    const float* bl    = (const float*)d_in[6];
    const float* W1    = (const float*)d_in[7];
    const float* b1    = (const float*)d_in[8];
    const float* W2    = (const float*)d_in[9];
    const float* b2    = (const float*)d_in[10];
    const float* Wc    = (const float*)d_in[11];
    const float* bc    = (const float*)d_in[12];
    float* out = (float*)d_out;

    hipLaunchKernelGGL(traj_kernel, dim3(512), dim3(512), 0, stream,
                       attrs, seq, Wd, bd, Wk, Wr, bl, W1, b1, W2, b2, Wc, bc, out);
}

// Round 11
// 324.557 us; speedup vs baseline: 2.0259x; 2.0259x over previous
//
#include <hip/hip_runtime.h>
#include <hip/hip_bf16.h>

#define T_LEN 200
#define F_IN 64
#define A_IN 128
#define H 100
#define H4 400
#define OUT_N 10
#define ROWS 16
#define NTHR 768

typedef __attribute__((ext_vector_type(8))) short bf16x8;
typedef __attribute__((ext_vector_type(4))) float f32x4;

#define NLOG2E -1.4426950408889634f

__device__ __forceinline__ unsigned short f2bf(float f) {
    union { float f; unsigned u; } v; v.f = f;
    unsigned r = v.u + 0x7FFFu + ((v.u >> 16) & 1u);
    return (unsigned short)(r >> 16);
}

__device__ __forceinline__ unsigned cvtpk(float lo, float hi) {
    unsigned r;
    asm("v_cvt_pk_bf16_f32 %0, %1, %2" : "=v"(r) : "v"(lo), "v"(hi));
    return r;
}

// sigmoid(z) where zp = -log2(e)*z came out of the MFMA (weights pre-scaled)
__device__ __forceinline__ float sigm2(float zp) {
    return __builtin_amdgcn_rcpf(1.0f + __builtin_amdgcn_exp2f(zp));
}

// LDS-only barrier: do NOT drain vmcnt (seq prefetch stays in flight)
__device__ __forceinline__ void lds_barrier() {
    asm volatile("s_waitcnt lgkmcnt(0)" ::: "memory");
    __builtin_amdgcn_s_barrier();
}

// h fragment slot for (batch b, hidden j): B-frag col=lane&15=b, k=lg*8+i
#define HOFF(b, j) ((((j) >> 5) * 64 + ((b) + 16 * (((j) >> 3) & 3))) * 8 + ((j) & 7))

extern "C" __global__ void __launch_bounds__(NTHR)
traj_kernel(const float* __restrict__ attrs, const float* __restrict__ seq,
            const float* __restrict__ Wd, const float* __restrict__ bd,
            const float* __restrict__ Wk, const float* __restrict__ Wr,
            const float* __restrict__ bl, const float* __restrict__ W1,
            const float* __restrict__ b1, const float* __restrict__ W2,
            const float* __restrict__ b2, const float* __restrict__ Wc,
            const float* __restrict__ bc, float* __restrict__ out)
{
    // LDS map (bytes), total 33792:
    //   [0, 8192)        hl    ushort[2][2048]  h bf16 B-frag double buffer
    //   [8192, 14592)    h32   float[16][100]   final h fp32
    //   [27648, 29696)   wk24  Wk A-frags tile 24 (wave-11-private)
    //   [29696, 33792)   wr24  Wr A-frags tile 24 (wave-11-private)
    // epilogue aliases (loop-dead regions): att [16][128]@0,
    //   catb [16][200]@14592 (ends 27392), x1b [16][100]@0,
    //   x2b [16][50]@8192 (h32 dead), lgb [16][10]@11392
    __shared__ __align__(16) char smem[33792];
    unsigned short* hl = (unsigned short*)smem;
    float* h32 = (float*)(smem + 8192);

    const int tid = threadIdx.x;
    const int lane = tid & 63;
    const int w = tid >> 6;            // 12 waves
    const int ln15 = lane & 15;
    const int lg = lane >> 4;
    const int b0 = blockIdx.x * ROWS;

    // tiles: wave w owns {2w, 2w+1} in registers; wave 11 also tile 24 via LDS
    const int nt0 = 2 * w;
    const bool w11 = (w == 11);

    // A-frag: lane holds row m=lane&15, k=(lane>>4)*8+i. Permuted row p=tile*16+m
    // -> original column c=(tile*4+(m>>2))+100*(m&3); D rows lg*4+r = gates i,f,g,o
    // of hidden j=tile*4+lg. Gates i,f,o pre-scaled by -log2(e) for exp2 sigmoid.
    const int rw = ln15 & 3;
    const int qr = ln15 >> 2;
    const float gsc = (rw == 2) ? 1.0f : NLOG2E;

    // ---- Wk frags in registers (2 tiles) ----
    bf16x8 wkf[2][2];
#pragma unroll
    for (int q = 0; q < 2; q++) {
        const int c = ((nt0 + q) * 4 + qr) + 100 * rw;
#pragma unroll
        for (int kt = 0; kt < 2; kt++) {
            bf16x8 f;
#pragma unroll
            for (int i = 0; i < 8; i++) {
                int k = kt * 32 + lg * 8 + i;
                f[i] = (short)f2bf(gsc * Wk[k * H4 + c]);
            }
            wkf[q][kt] = f;
        }
    }

    // ---- Wr frags in registers (2 tiles), bias folded into spare K-row k==100 ----
    bf16x8 wrf[2][4];
#pragma unroll
    for (int q = 0; q < 2; q++) {
        const int c = ((nt0 + q) * 4 + qr) + 100 * rw;
#pragma unroll
        for (int kt = 0; kt < 4; kt++) {
            bf16x8 f;
#pragma unroll
            for (int i = 0; i < 8; i++) {
                int k = kt * 32 + lg * 8 + i;
                float x = 0.0f;
                if (k < H) x = gsc * Wr[k * H4 + c];
                if (k == H) x = gsc * bl[c];   // bias row (h slot k=100 pinned to 1)
                f[i] = (short)f2bf(x);
            }
            wrf[q][kt] = f;
        }
    }

    // ---- wave 11: tile-24 Wk+Wr frags -> wave-private LDS ----
    if (w11) {
        const int c = (24 * 4 + qr) + 100 * rw;
#pragma unroll
        for (int kt = 0; kt < 2; kt++) {
            bf16x8 f;
#pragma unroll
            for (int i = 0; i < 8; i++) {
                int k = kt * 32 + lg * 8 + i;
                f[i] = (short)f2bf(gsc * Wk[k * H4 + c]);
            }
            *(bf16x8*)(smem + 27648 + kt * 1024 + lane * 16) = f;
        }
#pragma unroll
        for (int kt = 0; kt < 4; kt++) {
            bf16x8 f;
#pragma unroll
            for (int i = 0; i < 8; i++) {
                int k = kt * 32 + lg * 8 + i;
                float x = 0.0f;
                if (k < H) x = gsc * Wr[k * H4 + c];
                if (k == H) x = gsc * bl[c];
                f[i] = (short)f2bf(x);
            }
            *(bf16x8*)(smem + 29696 + kt * 1024 + lane * 16) = f;
        }
    }

    // gate destinations: batch b = ln15, hidden j
    const int ho0 = HOFF(ln15, nt0 * 4 + lg);
    const int ho1 = HOFF(ln15, (nt0 + 1) * 4 + lg);
    const int ho2 = HOFF(ln15, 96 + lg);     // w11's tile 24
    float cr0 = 0.f, cr1 = 0.f, cr2 = 0.f;
    float hq0 = 0.f, hq1 = 0.f, hq2 = 0.f;

    // zero both h buffers, then pin bias slot k=100 to bf16(1.0) in both
    for (int i = tid; i < 4096; i += NTHR) hl[i] = 0;
    __syncthreads();
    if (tid < 32) {
        int b = tid & 15, buf = tid >> 4;
        hl[buf * 2048 + 1536 + 8 * b + 4] = 0x3F80;  // (k=100, batch b) = 1.0
    }

    // ---- seq staging: lane = batch row ln15, feats lg*8..+7 and 32+lg*8..+7 ----
    const float* sp = seq + (size_t)(b0 + ln15) * (T_LEN * F_IN) + lg * 8;
    f32x4 s0 = *(const f32x4*)(sp);
    f32x4 s1 = *(const f32x4*)(sp + 4);
    f32x4 s2 = *(const f32x4*)(sp + 32);
    f32x4 s3 = *(const f32x4*)(sp + 36);
    sp += F_IN;

    const char* wk24p = smem + 27648 + lane * 16;
    const char* wr24p = smem + 29696 + lane * 16;
    f32x4 accX0, accX1, accX2;

    // prologue: accX = x(0)@Wk^T (C=0; bias arrives via Wr k=100 each step)
    {
        union { unsigned u[4]; bf16x8 v; } ua, ub;
        ua.u[0] = cvtpk(s0[0], s0[1]); ua.u[1] = cvtpk(s0[2], s0[3]);
        ua.u[2] = cvtpk(s1[0], s1[1]); ua.u[3] = cvtpk(s1[2], s1[3]);
        ub.u[0] = cvtpk(s2[0], s2[1]); ub.u[1] = cvtpk(s2[2], s2[3]);
        ub.u[2] = cvtpk(s3[0], s3[1]); ub.u[3] = cvtpk(s3[2], s3[3]);
        bf16x8 a0 = ua.v, a1 = ub.v;
        const f32x4 zz = { 0.f, 0.f, 0.f, 0.f };
        {
            f32x4 x = __builtin_amdgcn_mfma_f32_16x16x32_bf16(wkf[0][0], a0, zz, 0, 0, 0);
            accX0 = __builtin_amdgcn_mfma_f32_16x16x32_bf16(wkf[0][1], a1, x, 0, 0, 0);
            x = __builtin_amdgcn_mfma_f32_16x16x32_bf16(wkf[1][0], a0, zz, 0, 0, 0);
            accX1 = __builtin_amdgcn_mfma_f32_16x16x32_bf16(wkf[1][1], a1, x, 0, 0, 0);
        }
        if (w11) {
            bf16x8 wa = *(const bf16x8*)(wk24p);
            bf16x8 wb = *(const bf16x8*)(wk24p + 1024);
            f32x4 x = __builtin_amdgcn_mfma_f32_16x16x32_bf16(wa, a0, zz, 0, 0, 0);
            accX2 = __builtin_amdgcn_mfma_f32_16x16x32_bf16(wb, a1, x, 0, 0, 0);
        }
    }
    // issue load of x(1)
    s0 = *(const f32x4*)(sp);
    s1 = *(const f32x4*)(sp + 4);
    s2 = *(const f32x4*)(sp + 32);
    s3 = *(const f32x4*)(sp + 36);
    sp += F_IN;

    lds_barrier();   // hl zeros + bias pins visible (seq loads stay in flight)

    for (int t = 0; t < T_LEN; t++) {
        const bool notlast = (t < T_LEN - 1);

        // ---- read h(t-1) B-frags from buf[t&1]; w11 also tile-24 Wr frags ----
        const unsigned short* hp = hl + ((t & 1) << 11) + lane * 8;
        bf16x8 hf0 = *(const bf16x8*)(hp);
        bf16x8 hf1 = *(const bf16x8*)(hp + 512);
        bf16x8 hf2 = *(const bf16x8*)(hp + 1024);
        bf16x8 hf3 = *(const bf16x8*)(hp + 1536);
        bf16x8 w40, w41, w42, w43;
        if (w11) {
            w40 = *(const bf16x8*)(wr24p);
            w41 = *(const bf16x8*)(wr24p + 1024);
            w42 = *(const bf16x8*)(wr24p + 2048);
            w43 = *(const bf16x8*)(wr24p + 3072);
        }

        // cvt x(t+1) (overlaps LDS read latency)
        bf16x8 a0n = {}, a1n = {};
        if (notlast) {
            union { unsigned u[4]; bf16x8 v; } ua, ub;
            ua.u[0] = cvtpk(s0[0], s0[1]); ua.u[1] = cvtpk(s0[2], s0[3]);
            ua.u[2] = cvtpk(s1[0], s1[1]); ua.u[3] = cvtpk(s1[2], s1[3]);
            ub.u[0] = cvtpk(s2[0], s2[1]); ub.u[1] = cvtpk(s2[2], s2[3]);
            ub.u[2] = cvtpk(s3[0], s3[1]); ub.u[3] = cvtpk(s3[2], s3[3]);
            a0n = ua.v; a1n = ub.v;
        }

        // ---- accX += h(t-1)@Wr^T in place (+bias via k=100); kt-major ILP ----
        __builtin_amdgcn_s_setprio(1);
        accX0 = __builtin_amdgcn_mfma_f32_16x16x32_bf16(wrf[0][0], hf0, accX0, 0, 0, 0);
        accX1 = __builtin_amdgcn_mfma_f32_16x16x32_bf16(wrf[1][0], hf0, accX1, 0, 0, 0);
        if (w11) accX2 = __builtin_amdgcn_mfma_f32_16x16x32_bf16(w40, hf0, accX2, 0, 0, 0);
        accX0 = __builtin_amdgcn_mfma_f32_16x16x32_bf16(wrf[0][1], hf1, accX0, 0, 0, 0);
        accX1 = __builtin_amdgcn_mfma_f32_16x16x32_bf16(wrf[1][1], hf1, accX1, 0, 0, 0);
        if (w11) accX2 = __builtin_amdgcn_mfma_f32_16x16x32_bf16(w41, hf1, accX2, 0, 0, 0);
        accX0 = __builtin_amdgcn_mfma_f32_16x16x32_bf16(wrf[0][2], hf2, accX0, 0, 0, 0);
        accX1 = __builtin_amdgcn_mfma_f32_16x16x32_bf16(wrf[1][2], hf2, accX1, 0, 0, 0);
        if (w11) accX2 = __builtin_amdgcn_mfma_f32_16x16x32_bf16(w42, hf2, accX2, 0, 0, 0);
        accX0 = __builtin_amdgcn_mfma_f32_16x16x32_bf16(wrf[0][3], hf3, accX0, 0, 0, 0);
        accX1 = __builtin_amdgcn_mfma_f32_16x16x32_bf16(wrf[1][3], hf3, accX1, 0, 0, 0);
        if (w11) accX2 = __builtin_amdgcn_mfma_f32_16x16x32_bf16(w43, hf3, accX2, 0, 0, 0);
        __builtin_amdgcn_s_setprio(0);

        // prefetch x(t+2) (rides across the LDS barrier)
        if (t < T_LEN - 2) {
            s0 = *(const f32x4*)(sp);
            s1 = *(const f32x4*)(sp + 4);
            s2 = *(const f32x4*)(sp + 32);
            s3 = *(const f32x4*)(sp + 36);
            sp += F_IN;
        }

        // ---- gates in registers; write h(t) bf16 to buf[(t+1)&1] ----
        unsigned short* hwp = hl + (((t + 1) & 1) << 11);

#define DOGATE(AX, CR, HQ, HO) do {                                    \
            float _i = sigm2(AX[0]), _f = sigm2(AX[1]);                \
            float _g = fmaxf(AX[2], 0.0f), _o = sigm2(AX[3]);          \
            CR = _f * CR + _i * _g;                                    \
            float _h = _o * fmaxf(CR, 0.0f);                           \
            HQ = _h;                                                   \
            hwp[HO] = (unsigned short)cvtpk(_h, _h);                   \
        } while (0)

        DOGATE(accX0, cr0, hq0, ho0);
        DOGATE(accX1, cr1, hq1, ho1);
        if (w11) DOGATE(accX2, cr2, hq2, ho2);

        // ---- accX = x(t+1)@Wk^T (MFMA pipe, overlaps gate VALU) ----
        if (notlast) {
            const f32x4 zz = { 0.f, 0.f, 0.f, 0.f };
            f32x4 x = __builtin_amdgcn_mfma_f32_16x16x32_bf16(wkf[0][0], a0n, zz, 0, 0, 0);
            accX0 = __builtin_amdgcn_mfma_f32_16x16x32_bf16(wkf[0][1], a1n, x, 0, 0, 0);
            x = __builtin_amdgcn_mfma_f32_16x16x32_bf16(wkf[1][0], a0n, zz, 0, 0, 0);
            accX1 = __builtin_amdgcn_mfma_f32_16x16x32_bf16(wkf[1][1], a1n, x, 0, 0, 0);
            if (w11) {
                bf16x8 wa = *(const bf16x8*)(wk24p);
                bf16x8 wb = *(const bf16x8*)(wk24p + 1024);
                f32x4 y = __builtin_amdgcn_mfma_f32_16x16x32_bf16(wa, a0n, zz, 0, 0, 0);
                accX2 = __builtin_amdgcn_mfma_f32_16x16x32_bf16(wb, a1n, y, 0, 0, 0);
            }
        }

        lds_barrier();   // h(t) visible; protects buf WAR; vmem stays in flight
    }

    // ---- final h -> h32 (from persistent registers) ----
    h32[ln15 * H + nt0 * 4 + lg]       = hq0;
    h32[ln15 * H + (nt0 + 1) * 4 + lg] = hq1;
    if (w11) h32[ln15 * H + 96 + lg]   = hq2;

    // ---- epilogue: fp32 dense chain + softmax (ROWS=16, 768 threads) ----
    float* att  = (float*)smem;             // [16][128]
    float* catb = (float*)(smem + 14592);   // [16][200]
    float* x1b  = (float*)smem;             // [16][100]
    float* x2b  = (float*)(smem + 8192);    // [16][50]
    float* lgb  = (float*)(smem + 11392);   // [16][10]

    {
        f32x4 v = {0.f, 0.f, 0.f, 0.f};
        if (tid < 512) v = ((const f32x4*)(attrs + (size_t)b0 * A_IN))[tid];
        __syncthreads();                    // h32 writes + hl reads done; att overlays hl
        if (tid < 512) ((f32x4*)att)[tid] = v;   // 16x128 floats
    }
    __syncthreads();

#pragma unroll
    for (int k = 0; k < 3; k++) {
        int e = tid + NTHR * k;
        if (e < ROWS * H) {
            int b = e & 15, j = e >> 4;
            float s = bd[j];
            for (int kk = 0; kk < A_IN; kk++) s += att[b * A_IN + kk] * Wd[kk * H + j];
            catb[b * 200 + j] = fmaxf(s, 0.0f);
            catb[b * 200 + H + j] = h32[b * H + j];
        }
    }
    __syncthreads();

#pragma unroll
    for (int k = 0; k < 3; k++) {
        int e = tid + NTHR * k;
        if (e < ROWS * H) {
            int b = e & 15, j = e >> 4;
            float s = b1[j];
            for (int kk = 0; kk < 200; kk++) s += catb[b * 200 + kk] * W1[kk * H + j];
            x1b[b * H + j] = fmaxf(s, 0.0f);
        }
    }
    __syncthreads();

#pragma unroll
    for (int k = 0; k < 2; k++) {
        int e = tid + NTHR * k;
        if (e < ROWS * 50) {
            int b = e & 15, j = e >> 4;
            float s = b2[j];
            for (int kk = 0; kk < H; kk++) s += x1b[b * H + kk] * W2[kk * 50 + j];
            x2b[b * 50 + j] = fmaxf(s, 0.0f);
        }
    }
    __syncthreads();

    if (tid < ROWS * OUT_N) {
        int b = tid / OUT_N, o = tid % OUT_N;
        float s = bc[o];
        for (int kk = 0; kk < 50; kk++) s += x2b[b * 50 + kk] * Wc[kk * OUT_N + o];
        lgb[b * OUT_N + o] = s;
    }
    __syncthreads();

    if (tid < ROWS) {
        int b = tid;
        float m = -1e30f, v[10];
#pragma unroll
        for (int o = 0; o < 10; o++) { v[o] = lgb[b * 10 + o]; m = fmaxf(m, v[o]); }
        float ssum = 0.0f;
#pragma unroll
        for (int o = 0; o < 10; o++) { v[o] = __expf(v[o] - m); ssum += v[o]; }
        float inv = 1.0f / ssum;
#pragma unroll
        for (int o = 0; o < 10; o++) out[(size_t)(b0 + b) * 10 + o] = v[o] * inv;
    }
}

extern "C" void kernel_launch(void* const* d_in, const int* in_sizes, int n_in,
                              void* d_out, int out_size, void* d_ws, size_t ws_size,
                              hipStream_t stream) {
    const float* attrs = (const float*)d_in[0];
    const float* seq   = (const float*)d_in[1];
    const float* Wd    = (const float*)d_in[2];
    const float* bd    = (const float*)d_in[3];
    const float* Wk    = (const float*)d_in[4];
    const float* Wr    = (const float*)d_in[5];
    const float* bl    = (const float*)d_in[6];
    const float* W1    = (const float*)d_in[7];
    const float* b1    = (const float*)d_in[8];
    const float* W2    = (const float*)d_in[9];
    const float* b2    = (const float*)d_in[10];
    const float* Wc    = (const float*)d_in[11];
    const float* bc    = (const float*)d_in[12];
    float* out = (float*)d_out;

    hipLaunchKernelGGL(traj_kernel, dim3(256), dim3(NTHR), 0, stream,
                       attrs, seq, Wd, bd, Wk, Wr, bl, W1, b1, W2, b2, Wc, bc, out);
}

// Round 12
// 246.500 us; speedup vs baseline: 2.6674x; 1.3167x over previous
//
#include <hip/hip_runtime.h>
#include <hip/hip_bf16.h>

#define T_LEN 200
#define F_IN 64
#define A_IN 128
#define H 100
#define H4 400
#define OUT_N 10
#define ROWS 16

typedef __attribute__((ext_vector_type(8))) short bf16x8;
typedef __attribute__((ext_vector_type(4))) float f32x4;

#define NLOG2E -1.4426950408889634f

__device__ __forceinline__ unsigned short f2bf(float f) {
    union { float f; unsigned u; } v; v.f = f;
    unsigned r = v.u + 0x7FFFu + ((v.u >> 16) & 1u);
    return (unsigned short)(r >> 16);
}

__device__ __forceinline__ unsigned cvtpk(float lo, float hi) {
    unsigned r;
    asm("v_cvt_pk_bf16_f32 %0, %1, %2" : "=v"(r) : "v"(lo), "v"(hi));
    return r;
}

// sigmoid(z) where zp = -log2(e)*z came out of the MFMA (weights pre-scaled)
__device__ __forceinline__ float sigm2(float zp) {
    return __builtin_amdgcn_rcpf(1.0f + __builtin_amdgcn_exp2f(zp));
}

// LDS-only barrier: do NOT drain vmcnt (seq prefetch stays in flight)
__device__ __forceinline__ void lds_barrier() {
    asm volatile("s_waitcnt lgkmcnt(0)" ::: "memory");
    __builtin_amdgcn_s_barrier();
}

// h fragment slot for (batch b, hidden j): B-frag col=lane&15=b, k=lg*8+i
#define HOFF(b, j) ((((j) >> 5) * 64 + ((b) + 16 * (((j) >> 3) & 3))) * 8 + ((j) & 7))

extern "C" __global__ void __launch_bounds__(512, 2)
traj_kernel(const float* __restrict__ attrs, const float* __restrict__ seq,
            const float* __restrict__ Wd, const float* __restrict__ bd,
            const float* __restrict__ Wk, const float* __restrict__ Wr,
            const float* __restrict__ bl, const float* __restrict__ W1,
            const float* __restrict__ b1, const float* __restrict__ W2,
            const float* __restrict__ b2, const float* __restrict__ Wc,
            const float* __restrict__ bc, float* __restrict__ out)
{
    // LDS map (bytes), total 27648:
    //   [0, 8192)       hl   ushort[2][2048]  h bf16 B-frag double buffer
    //   [8192, 14592)   h32  float[16][100]   final h fp32
    //   [14592, 27392)  catb float[16][200]   (epilogue)
    // epilogue aliases (loop-dead): att [16][128]@0, x1b [16][100]@0,
    //   x2b [16][50]@8192 (h32 dead after catb), lgb [16][10]@11392
    __shared__ __align__(16) char smem[27648];
    unsigned short* hl = (unsigned short*)smem;
    float* h32 = (float*)(smem + 8192);

    const int tid = threadIdx.x;
    const int lane = tid & 63;
    const int w = tid >> 6;
    const int ln15 = lane & 15;
    const int lg = lane >> 4;
    const int b0 = blockIdx.x * ROWS;

    // output-dim tiles (Z^T rows): waves 0..6 own {3w..3w+2}; wave 7 owns {21..24}
    const int nt0 = 3 * w;
    const int ntc = (w == 7) ? 4 : 3;
    const bool w7 = (w == 7);

    // A-frag: lane holds row m=lane&15, k=(lane>>4)*8+i. Permuted row p=tile*16+m
    // -> original column c=(tile*4+(m>>2))+100*(m&3); D rows lg*4+r = gates i,f,g,o
    // of hidden j=tile*4+lg. Gates i,f,o pre-scaled by -log2(e) for exp2 sigmoid.
    const int rw = ln15 & 3;
    const int qr = ln15 >> 2;
    const float gsc = (rw == 2) ? 1.0f : NLOG2E;

    // ---- Wk frags in registers ----
    bf16x8 wkf[4][2];
#pragma unroll
    for (int q = 0; q < 4; q++) {
        const bool v = (q < ntc);
        const int c = v ? ((nt0 + q) * 4 + qr) + 100 * rw : 0;
#pragma unroll
        for (int kt = 0; kt < 2; kt++) {
            bf16x8 f;
#pragma unroll
            for (int i = 0; i < 8; i++) {
                int k = kt * 32 + lg * 8 + i;
                f[i] = (short)f2bf(v ? gsc * Wk[k * H4 + c] : 0.0f);
            }
            wkf[q][kt] = f;
        }
    }

    // ---- Wr frags in registers, bias folded into spare K-row k==100 (kt=3) ----
    bf16x8 wrf[4][4];
#pragma unroll
    for (int q = 0; q < 4; q++) {
        const bool v = (q < ntc);
        const int c = v ? ((nt0 + q) * 4 + qr) + 100 * rw : 0;
#pragma unroll
        for (int kt = 0; kt < 4; kt++) {
            bf16x8 f;
#pragma unroll
            for (int i = 0; i < 8; i++) {
                int k = kt * 32 + lg * 8 + i;
                float x = 0.0f;
                if (v && k < H) x = gsc * Wr[k * H4 + c];
                if (v && k == H) x = gsc * bl[c];   // bias row (h slot k=100 pinned to 1)
                f[i] = (short)f2bf(x);
            }
            wrf[q][kt] = f;
        }
    }

    // gate destinations: batch b = ln15, hidden j_q = (nt0+q)*4 + lg
    int hoq[4];
#pragma unroll
    for (int q = 0; q < 4; q++) {
        int j = (nt0 + q) * 4 + lg;
        if (j > 99) j = 99;  // inactive q only
        hoq[q] = HOFF(ln15, j);
    }
    float cr0 = 0.f, cr1 = 0.f, cr2 = 0.f, cr3 = 0.f;
    float hq0 = 0.f, hq1 = 0.f, hq2 = 0.f, hq3 = 0.f;  // persistent last-h

    // zero both h buffers, then pin bias slot k=100 to bf16(1.0) in both
    for (int i = tid; i < 4096; i += 512) hl[i] = 0;
    __syncthreads();
    if (tid < 32) {
        int b = tid & 15, buf = tid >> 4;
        hl[buf * 2048 + 1536 + 8 * b + 4] = 0x3F80;  // (k=100, batch b) = 1.0
    }

    // ---- seq staging: lane = batch row ln15, feats lg*8..+7 and 32+lg*8..+7 ----
    const float* sp = seq + (size_t)(b0 + ln15) * (T_LEN * F_IN) + lg * 8;
    f32x4 s0 = *(const f32x4*)(sp);
    f32x4 s1 = *(const f32x4*)(sp + 4);
    f32x4 s2 = *(const f32x4*)(sp + 32);
    f32x4 s3 = *(const f32x4*)(sp + 36);
    sp += F_IN;

    // precomputed LDS pointers (both parities; unroll-2 makes selects free)
    const unsigned short* hpA = hl + lane * 8;          // read buf for even t
    const unsigned short* hpB = hl + 2048 + lane * 8;   // read buf for odd t
    unsigned short* hwA = hl + 2048;                    // write buf for even t
    unsigned short* hwB = hl;                           // write buf for odd t

    // prologue: accX = x(0)@Wk^T  (C=0; bias arrives via Wr kt=3 each step)
    f32x4 accX[4];
    {
        union { unsigned u[4]; bf16x8 v; } ua, ub;
        ua.u[0] = cvtpk(s0[0], s0[1]); ua.u[1] = cvtpk(s0[2], s0[3]);
        ua.u[2] = cvtpk(s1[0], s1[1]); ua.u[3] = cvtpk(s1[2], s1[3]);
        ub.u[0] = cvtpk(s2[0], s2[1]); ub.u[1] = cvtpk(s2[2], s2[3]);
        ub.u[2] = cvtpk(s3[0], s3[1]); ub.u[3] = cvtpk(s3[2], s3[3]);
        bf16x8 a0 = ua.v, a1 = ub.v;
        const f32x4 zz = { 0.f, 0.f, 0.f, 0.f };
#pragma unroll
        for (int q = 0; q < 3; q++) {
            f32x4 x = __builtin_amdgcn_mfma_f32_16x16x32_bf16(wkf[q][0], a0, zz, 0, 0, 0);
            accX[q] = __builtin_amdgcn_mfma_f32_16x16x32_bf16(wkf[q][1], a1, x, 0, 0, 0);
        }
        if (w7) {
            f32x4 x = __builtin_amdgcn_mfma_f32_16x16x32_bf16(wkf[3][0], a0, zz, 0, 0, 0);
            accX[3] = __builtin_amdgcn_mfma_f32_16x16x32_bf16(wkf[3][1], a1, x, 0, 0, 0);
        }
    }
    // issue load of x(1)
    s0 = *(const f32x4*)(sp);
    s1 = *(const f32x4*)(sp + 4);
    s2 = *(const f32x4*)(sp + 32);
    s3 = *(const f32x4*)(sp + 36);
    sp += F_IN;

    lds_barrier();   // hl zeros + bias pins visible (seq loads stay in flight)

#pragma unroll 2
    for (int t = 0; t < T_LEN; t++) {
        const bool notlast = (t < T_LEN - 1);
        const bool even = ((t & 1) == 0);

        // ---- read h(t-1) B-frags from parity buffer ----
        const unsigned short* hp = even ? hpA : hpB;
        bf16x8 hf0 = *(const bf16x8*)(hp);
        bf16x8 hf1 = *(const bf16x8*)(hp + 512);
        bf16x8 hf2 = *(const bf16x8*)(hp + 1024);
        bf16x8 hf3 = *(const bf16x8*)(hp + 1536);

        // cvt x(t+1) (overlaps h-frag read latency)
        bf16x8 a0n = {}, a1n = {};
        if (notlast) {
            union { unsigned u[4]; bf16x8 v; } ua, ub;
            ua.u[0] = cvtpk(s0[0], s0[1]); ua.u[1] = cvtpk(s0[2], s0[3]);
            ua.u[2] = cvtpk(s1[0], s1[1]); ua.u[3] = cvtpk(s1[2], s1[3]);
            ub.u[0] = cvtpk(s2[0], s2[1]); ub.u[1] = cvtpk(s2[2], s2[3]);
            ub.u[2] = cvtpk(s3[0], s3[1]); ub.u[3] = cvtpk(s3[2], s3[3]);
            a0n = ua.v; a1n = ub.v;
        }

        // ---- rr = accX + h(t-1)@Wr^T, split 2+2 to halve the dependent chain:
        //      chain A: accX <- kt0,kt1 ; chain B (fresh): kt2,kt3 (carries bias)
        f32x4 rr[4], rb[4];
        const f32x4 zz = { 0.f, 0.f, 0.f, 0.f };
        __builtin_amdgcn_s_setprio(1);
#pragma unroll
        for (int q = 0; q < 3; q++)
            rr[q] = __builtin_amdgcn_mfma_f32_16x16x32_bf16(wrf[q][0], hf0, accX[q], 0, 0, 0);
        if (w7)
            rr[3] = __builtin_amdgcn_mfma_f32_16x16x32_bf16(wrf[3][0], hf0, accX[3], 0, 0, 0);
#pragma unroll
        for (int q = 0; q < 3; q++)
            rb[q] = __builtin_amdgcn_mfma_f32_16x16x32_bf16(wrf[q][2], hf2, zz, 0, 0, 0);
        if (w7)
            rb[3] = __builtin_amdgcn_mfma_f32_16x16x32_bf16(wrf[3][2], hf2, zz, 0, 0, 0);
#pragma unroll
        for (int q = 0; q < 3; q++)
            rr[q] = __builtin_amdgcn_mfma_f32_16x16x32_bf16(wrf[q][1], hf1, rr[q], 0, 0, 0);
        if (w7)
            rr[3] = __builtin_amdgcn_mfma_f32_16x16x32_bf16(wrf[3][1], hf1, rr[3], 0, 0, 0);
#pragma unroll
        for (int q = 0; q < 3; q++)
            rb[q] = __builtin_amdgcn_mfma_f32_16x16x32_bf16(wrf[q][3], hf3, rb[q], 0, 0, 0);
        if (w7)
            rb[3] = __builtin_amdgcn_mfma_f32_16x16x32_bf16(wrf[3][3], hf3, rb[3], 0, 0, 0);
        __builtin_amdgcn_s_setprio(0);

        // prefetch x(t+2) (rides across the LDS barrier)
        if (t < T_LEN - 2) {
            s0 = *(const f32x4*)(sp);
            s1 = *(const f32x4*)(sp + 4);
            s2 = *(const f32x4*)(sp + 32);
            s3 = *(const f32x4*)(sp + 36);
            sp += F_IN;
        }

        // ---- merge chains + gates in registers; write h(t) to parity buffer ----
        unsigned short* hwp = even ? hwA : hwB;

#define DOGATE(RRQ, RBQ, CR, HQ, Q) do {                               \
            f32x4 _z = RRQ + RBQ;                                      \
            float _i = sigm2(_z[0]), _f = sigm2(_z[1]);                \
            float _g = fmaxf(_z[2], 0.0f), _o = sigm2(_z[3]);          \
            CR = _f * CR + _i * _g;                                    \
            float _h = _o * fmaxf(CR, 0.0f);                           \
            HQ = _h;                                                   \
            hwp[hoq[Q]] = (unsigned short)cvtpk(_h, _h);               \
        } while (0)

        DOGATE(rr[0], rb[0], cr0, hq0, 0);
        DOGATE(rr[1], rb[1], cr1, hq1, 1);
        DOGATE(rr[2], rb[2], cr2, hq2, 2);
        if (w7) DOGATE(rr[3], rb[3], cr3, hq3, 3);

        // ---- accX = x(t+1)@Wk^T (MFMA pipe, overlaps gate VALU) ----
        if (notlast) {
#pragma unroll
            for (int q = 0; q < 3; q++) {
                f32x4 x = __builtin_amdgcn_mfma_f32_16x16x32_bf16(wkf[q][0], a0n, zz, 0, 0, 0);
                accX[q] = __builtin_amdgcn_mfma_f32_16x16x32_bf16(wkf[q][1], a1n, x, 0, 0, 0);
            }
            if (w7) {
                f32x4 x = __builtin_amdgcn_mfma_f32_16x16x32_bf16(wkf[3][0], a0n, zz, 0, 0, 0);
                accX[3] = __builtin_amdgcn_mfma_f32_16x16x32_bf16(wkf[3][1], a1n, x, 0, 0, 0);
            }
        }

        lds_barrier();   // h(t) visible; protects buf WAR; vmem stays in flight
    }

    // ---- final h -> h32 (from persistent registers) ----
#pragma unroll
    for (int q = 0; q < 3; q++)
        h32[ln15 * H + (nt0 + q) * 4 + lg] = (q == 0) ? hq0 : (q == 1) ? hq1 : hq2;
    if (w7) h32[ln15 * H + 24 * 4 + lg] = hq3;

    // ---- epilogue: fp32 dense chain + softmax ----
    float* att  = (float*)smem;             // [16][128]
    float* catb = (float*)(smem + 14592);   // [16][200]
    float* x1b  = (float*)smem;             // [16][100]
    float* x2b  = (float*)(smem + 8192);    // [16][50]
    float* lgb  = (float*)(smem + 11392);   // [16][10]

    {
        const f32x4* src = (const f32x4*)(attrs + (size_t)b0 * A_IN);
        f32x4 v = src[tid];
        __syncthreads();                    // h32 writes + hl reads done; att overlays hl
        ((f32x4*)att)[tid] = v;             // 16x128 floats
    }
    __syncthreads();

#pragma unroll
    for (int k = 0; k < 4; k++) {
        int e = tid + 512 * k;
        if (e < ROWS * H) {
            int b = e & 15, j = e >> 4;
            float s = bd[j];
            for (int kk = 0; kk < A_IN; kk++) s += att[b * A_IN + kk] * Wd[kk * H + j];
            catb[b * 200 + j] = fmaxf(s, 0.0f);
            catb[b * 200 + H + j] = h32[b * H + j];
        }
    }
    __syncthreads();

#pragma unroll
    for (int k = 0; k < 4; k++) {
        int e = tid + 512 * k;
        if (e < ROWS * H) {
            int b = e & 15, j = e >> 4;
            float s = b1[j];
            for (int kk = 0; kk < 200; kk++) s += catb[b * 200 + kk] * W1[kk * H + j];
            x1b[b * H + j] = fmaxf(s, 0.0f);
        }
    }
    __syncthreads();

#pragma unroll
    for (int k = 0; k < 2; k++) {
        int e = tid + 512 * k;
        if (e < ROWS * 50) {
            int b = e & 15, j = e >> 4;
            float s = b2[j];
            for (int kk = 0; kk < H; kk++) s += x1b[b * H + kk] * W2[kk * 50 + j];
            x2b[b * 50 + j] = fmaxf(s, 0.0f);
        }
    }
    __syncthreads();

    if (tid < ROWS * OUT_N) {
        int b = tid / OUT_N, o = tid % OUT_N;
        float s = bc[o];
        for (int kk = 0; kk < 50; kk++) s += x2b[b * 50 + kk] * Wc[kk * OUT_N + o];
        lgb[b * OUT_N + o] = s;
    }
    __syncthreads();

    if (tid < ROWS) {
        int b = tid;
        float m = -1e30f, v[10];
#pragma unroll
        for (int o = 0; o < 10; o++) { v[o] = lgb[b * 10 + o]; m = fmaxf(m, v[o]); }
        float ssum = 0.0f;
#pragma unroll
        for (int o = 0; o < 10; o++) { v[o] = __expf(v[o] - m); ssum += v[o]; }
        float inv = 1.0f / ssum;
#pragma unroll
        for (int o = 0; o < 10; o++) out[(size_t)(b0 + b) * 10 + o] = v[o] * inv;
    }
}

extern "C" void kernel_launch(void* const* d_in, const int* in_sizes, int n_in,
                              void* d_out, int out_size, void* d_ws, size_t ws_size,
                              hipStream_t stream) {
    const float* attrs = (const float*)d_in[0];
    const float* seq   = (const float*)d_in[1];
    const float* Wd    = (const float*)d_in[2];
    const float* bd    = (const float*)d_in[3];
    const float* Wk    = (const float*)d_in[4];
    const float* Wr    = (const float*)d_in[5];
    const float* bl    = (const float*)d_in[6];
    const float* W1    = (const float*)d_in[7];
    const float* b1    = (const float*)d_in[8];
    const float* W2    = (const float*)d_in[9];
    const float* b2    = (const float*)d_in[10];
    const float* Wc    = (const float*)d_in[11];
    const float* bc    = (const float*)d_in[12];
    float* out = (float*)d_out;

    hipLaunchKernelGGL(traj_kernel, dim3(256), dim3(512), 0, stream,
                       attrs, seq, Wd, bd, Wk, Wr, bl, W1, b1, W2, b2, Wc, bc, out);
}